// Round 8
// baseline (188.498 us; speedup 1.0000x reference)
//
#include <hip/hip_runtime.h>

#define NN 100000
#define NE 1600000
#define FIN 32
#define FHID 64

#define CLB 7                                   // log2(nodes per bucket)
#define BN (1 << CLB)                           // 128 nodes / bucket
#define NB ((NN + BN - 1) / BN)                 // 782 buckets
#define NDB 256                                 // distributor blocks
#define CHUNK ((NE + NDB - 1) / NDB)            // 6250 edges / distributor block
#define NSC (NB * NDB)                          // 200192 scan elements
#define SCAN_B 1024
#define SCAN_NB ((NSC + SCAN_B - 1) / SCAN_B)   // 196

#define LGKM0 asm volatile("s_waitcnt lgkmcnt(0)" ::: "memory")

__device__ __forceinline__ float lo16(unsigned g) {
    return __uint_as_float(g << 16);
}
__device__ __forceinline__ float hi16(unsigned g) {
    return __uint_as_float(g & 0xFFFF0000u);
}
__device__ __forceinline__ unsigned pack_bf16(float a, float b) {
    unsigned ua = __float_as_uint(a);
    unsigned ub = __float_as_uint(b);
    ua += 0x7FFFu + ((ua >> 16) & 1u);          // RNE
    ub += 0x7FFFu + ((ub >> 16) & 1u);
    return (ua >> 16) | (ub & 0xFFFF0000u);
}

// ---------- pass 1: per-(bucket, block) histogram, bucket-major layout --------
__global__ void k_dcount(const int* __restrict__ col, int* __restrict__ hist_g) {
    __shared__ int hc[NB];
    for (int i = threadIdx.x; i < NB; i += blockDim.x) hc[i] = 0;
    __syncthreads();
    int beg = blockIdx.x * CHUNK, end = min(beg + CHUNK, NE);
    for (int e = beg + threadIdx.x; e < end; e += blockDim.x)
        atomicAdd(&hc[col[e] >> CLB], 1);
    __syncthreads();
    for (int i = threadIdx.x; i < NB; i += blockDim.x)
        hist_g[i * NDB + blockIdx.x] = hc[i];
}

// ---------- exclusive scan over NSC ints (3 kernels) ----------
__global__ void k_scan1(const int* __restrict__ in, int* __restrict__ out,
                        int* __restrict__ bsum) {
    __shared__ int s[SCAN_B];
    int i = blockIdx.x * SCAN_B + threadIdx.x;
    int v = (i < NSC) ? in[i] : 0;
    s[threadIdx.x] = v;
    __syncthreads();
    for (int o = 1; o < SCAN_B; o <<= 1) {
        int t = (threadIdx.x >= o) ? s[threadIdx.x - o] : 0;
        __syncthreads();
        s[threadIdx.x] += t;
        __syncthreads();
    }
    if (i < NSC) out[i] = s[threadIdx.x] - v;  // exclusive
    if (threadIdx.x == SCAN_B - 1) bsum[blockIdx.x] = s[SCAN_B - 1];
}

__global__ void k_scan2(int* __restrict__ bsum) {   // 1 block, 256 threads
    __shared__ int s[256];
    int v = (threadIdx.x < SCAN_NB) ? bsum[threadIdx.x] : 0;
    s[threadIdx.x] = v;
    __syncthreads();
    for (int o = 1; o < 256; o <<= 1) {
        int t = (threadIdx.x >= o) ? s[threadIdx.x - o] : 0;
        __syncthreads();
        s[threadIdx.x] += t;
        __syncthreads();
    }
    if (threadIdx.x < SCAN_NB) bsum[threadIdx.x] = s[threadIdx.x] - v;  // exclusive
}

__global__ void k_scan3(int* __restrict__ out, const int* __restrict__ bsum) {
    int i = blockIdx.x * blockDim.x + threadIdx.x;
    if (i < NSC) out[i] += bsum[i >> 10];
}

// ---------- pass 2: write bucketed records (no global atomics) ----------------
// record = ((col_local << 17) | src, ew_bits)
__global__ void k_dwrite(const int* __restrict__ row, const int* __restrict__ col,
                         const float* __restrict__ ew, const int* __restrict__ base_g,
                         uint2* __restrict__ rec0) {
    __shared__ int rk[NB];
    __shared__ int bl[NB];
    for (int i = threadIdx.x; i < NB; i += blockDim.x) {
        rk[i] = 0;
        bl[i] = base_g[i * NDB + blockIdx.x];
    }
    __syncthreads();
    int beg = blockIdx.x * CHUNK, end = min(beg + CHUNK, NE);
    for (int e = beg + threadIdx.x; e < end; e += blockDim.x) {
        int c = col[e];
        int bk = c >> CLB;
        int r = atomicAdd(&rk[bk], 1);
        unsigned pack = ((unsigned)(c & (BN - 1)) << 17) | (unsigned)row[e];
        rec0[bl[bk] + r] = make_uint2(pack, __float_as_uint(ew[e]));
    }
}

// ---------- per-bucket sort -> exact per-node CSR + degree/dinv ---------------
__global__ void k_bsort(const int* __restrict__ base_g, const uint2* __restrict__ rec0,
                        uint2* __restrict__ csr, int* __restrict__ rowptr,
                        float* __restrict__ dinv) {
    __shared__ int cnt[BN];
    __shared__ int bas[BN];
    __shared__ int cur[BN];
    __shared__ float dg[BN];
    int tid = threadIdx.x;
    int b = blockIdx.x;
    int beg = base_g[b * NDB];
    int end = (b == NB - 1) ? NE : base_g[(b + 1) * NDB];
    if (tid < BN) { cnt[tid] = 0; dg[tid] = 0.0f; }
    __syncthreads();
    for (int j = beg + tid; j < end; j += blockDim.x) {
        uint2 p = rec0[j];
        int cl = p.x >> 17;
        atomicAdd(&cnt[cl], 1);
        atomicAdd(&dg[cl], __uint_as_float(p.y));
    }
    __syncthreads();
    int v0 = (tid < BN) ? cnt[tid] : 0;
    __syncthreads();
    for (int o = 1; o < BN; o <<= 1) {               // Hillis-Steele inclusive
        int t = (tid < BN && tid >= o) ? cnt[tid - o] : 0;
        __syncthreads();
        if (tid < BN) cnt[tid] += t;
        __syncthreads();
    }
    if (tid < BN) {
        int excl = cnt[tid] - v0;
        bas[tid] = excl;
        cur[tid] = 0;
        int node = b * BN + tid;
        if (node < NN) {
            rowptr[node] = beg + excl;
            dinv[node] = rsqrtf(1.0f + dg[tid]);     // self-loop weight 1
        }
    }
    if (b == 0 && tid == 0) rowptr[NN] = NE;
    __syncthreads();
    for (int j = beg + tid; j < end; j += blockDim.x) {
        uint2 p = rec0[j];
        int cl = p.x >> 17;
        int r = atomicAdd(&cur[cl], 1);
        csr[beg + bas[cl] + r] = make_uint2(p.x & 0x1FFFFu, p.y);
    }
}

// ---------- xp = bf16x2-packed dinv*x ----------------------------------------
__global__ void k_scalex(const float* __restrict__ x, const float* __restrict__ dinv,
                         unsigned* __restrict__ xp) {
    int idx = blockIdx.x * blockDim.x + threadIdx.x;   // pair index
    if (idx >= NN * (FIN / 2)) return;
    float dn = dinv[idx >> 4];
    float2 v = ((const float2*)x)[idx];
    xp[idx] = pack_bf16(v.x * dn, v.y * dn);
}

// ---------- layer 1 fused: agg + GEMM1(+b1,relu) + GEMM2 + dinv  -> hw2p ------
// Wave layout: slot s = lane>>2 owns edge j = beg+s (step 16);
// u = lane&3 owns feature octet (8u..8u+7) as uint4 of bf16x2.
__global__ __launch_bounds__(256, 4) void k_agg1f(
        const int* __restrict__ rowptr, const uint2* __restrict__ csr,
        const uint4* __restrict__ xp4, const float* __restrict__ dinv,
        const float* __restrict__ W1, const float* __restrict__ b1,
        const float* __restrict__ W2, unsigned* __restrict__ hw2p, int nwaves) {
    __shared__ float pre_lds[4 * FIN];
    __shared__ float hv_lds[4 * FHID];
    int lane = threadIdx.x & 63;
    int ws = threadIdx.x >> 6;          // wave slot in block
    int s = lane >> 2;                  // edge slot 0..15
    int u = lane & 3;                   // feature-octet index
    int hh = lane >> 5;
    int f = lane & 31;
    int t = lane & 15;
    int o = lane;                       // 0..63
    // register-resident weights (launch_bounds(256,4) -> 128 VGPR budget)
    float W1col[FIN];
#pragma unroll
    for (int k = 0; k < FIN; ++k) W1col[k] = W1[k * FHID + o];
    float b1o = b1[o];
    float W2h[FIN];
#pragma unroll
    for (int k = 0; k < FIN; ++k) W2h[k] = W2[(hh * 32 + k) * FIN + f];

    int gw = (blockIdx.x * blockDim.x + threadIdx.x) >> 6;
    for (int n = gw; n < NN; n += nwaves) {
        int beg = rowptr[n], end = rowptr[n + 1];
        float dn = dinv[n];                          // hoisted: overlap w/ loop
        uint4 gs = xp4[(size_t)n * 4 + u];
        float c0 = 0.f, c1 = 0.f, c2 = 0.f, c3 = 0.f;
        float c4 = 0.f, c5 = 0.f, c6 = 0.f, c7 = 0.f;
        float d0 = 0.f, d1 = 0.f, d2 = 0.f, d3 = 0.f;
        float d4 = 0.f, d5 = 0.f, d6 = 0.f, d7 = 0.f;
        int j = beg + s;
        for (; j + 16 < end; j += 32) {
            uint2 e0 = csr[j];
            uint2 e1 = csr[j + 16];
            uint4 g0 = xp4[(size_t)e0.x * 4 + u];
            uint4 g1 = xp4[(size_t)e1.x * 4 + u];
            float w0 = __uint_as_float(e0.y);
            float w1 = __uint_as_float(e1.y);
            c0 = fmaf(w0, lo16(g0.x), c0);
            c1 = fmaf(w0, hi16(g0.x), c1);
            c2 = fmaf(w0, lo16(g0.y), c2);
            c3 = fmaf(w0, hi16(g0.y), c3);
            c4 = fmaf(w0, lo16(g0.z), c4);
            c5 = fmaf(w0, hi16(g0.z), c5);
            c6 = fmaf(w0, lo16(g0.w), c6);
            c7 = fmaf(w0, hi16(g0.w), c7);
            d0 = fmaf(w1, lo16(g1.x), d0);
            d1 = fmaf(w1, hi16(g1.x), d1);
            d2 = fmaf(w1, lo16(g1.y), d2);
            d3 = fmaf(w1, hi16(g1.y), d3);
            d4 = fmaf(w1, lo16(g1.z), d4);
            d5 = fmaf(w1, hi16(g1.z), d5);
            d6 = fmaf(w1, lo16(g1.w), d6);
            d7 = fmaf(w1, hi16(g1.w), d7);
        }
        for (; j < end; j += 16) {
            uint2 e = csr[j];
            uint4 g = xp4[(size_t)e.x * 4 + u];
            float w = __uint_as_float(e.y);
            c0 = fmaf(w, lo16(g.x), c0);
            c1 = fmaf(w, hi16(g.x), c1);
            c2 = fmaf(w, lo16(g.y), c2);
            c3 = fmaf(w, hi16(g.y), c3);
            c4 = fmaf(w, lo16(g.z), c4);
            c5 = fmaf(w, hi16(g.z), c5);
            c6 = fmaf(w, lo16(g.w), c6);
            c7 = fmaf(w, hi16(g.w), c7);
        }
        c0 += d0; c1 += d1; c2 += d2; c3 += d3;
        c4 += d4; c5 += d5; c6 += d6; c7 += d7;
        // reduce across 16 slots (lane bits 2..5)
#pragma unroll
        for (int m = 4; m <= 32; m <<= 1) {
            c0 += __shfl_xor(c0, m, 64);
            c1 += __shfl_xor(c1, m, 64);
            c2 += __shfl_xor(c2, m, 64);
            c3 += __shfl_xor(c3, m, 64);
            c4 += __shfl_xor(c4, m, 64);
            c5 += __shfl_xor(c5, m, 64);
            c6 += __shfl_xor(c6, m, 64);
            c7 += __shfl_xor(c7, m, 64);
        }
        if (s == 0) {                               // lanes 0..3
            float4 p0, p1;
            p0.x = dn * (c0 + lo16(gs.x));
            p0.y = dn * (c1 + hi16(gs.x));
            p0.z = dn * (c2 + lo16(gs.y));
            p0.w = dn * (c3 + hi16(gs.y));
            p1.x = dn * (c4 + lo16(gs.z));
            p1.y = dn * (c5 + hi16(gs.z));
            p1.z = dn * (c6 + lo16(gs.w));
            p1.w = dn * (c7 + hi16(gs.w));
            *(float4*)&pre_lds[ws * FIN + 8 * u] = p0;
            *(float4*)&pre_lds[ws * FIN + 8 * u + 4] = p1;
        }
        LGKM0;
        // GEMM1: h_o = relu(b1 + sum_k pre[k] * W1[k][o])
        float hacc = b1o;
#pragma unroll
        for (int i = 0; i < 8; ++i) {
            float4 qd = *(const float4*)&pre_lds[ws * FIN + 4 * i];
            hacc = fmaf(qd.x, W1col[4 * i + 0], hacc);
            hacc = fmaf(qd.y, W1col[4 * i + 1], hacc);
            hacc = fmaf(qd.z, W1col[4 * i + 2], hacc);
            hacc = fmaf(qd.w, W1col[4 * i + 3], hacc);
        }
        hacc = hacc > 0.0f ? hacc : 0.0f;
        hv_lds[ws * FHID + o] = hacc;
        LGKM0;
        // GEMM2 (halves split o-range): v[f] = dn * sum_o h_o W2[o][f]
        float part = 0.0f;
#pragma unroll
        for (int i = 0; i < 8; ++i) {
            float4 qd = *(const float4*)&hv_lds[ws * FHID + hh * 32 + 4 * i];
            part = fmaf(qd.x, W2h[4 * i + 0], part);
            part = fmaf(qd.y, W2h[4 * i + 1], part);
            part = fmaf(qd.z, W2h[4 * i + 2], part);
            part = fmaf(qd.w, W2h[4 * i + 3], part);
        }
        part += __shfl_xor(part, 32, 64);    // all lanes: final v for f=lane&31
        float v = dn * part;
        float vlo = __shfl(v, 2 * t, 64);
        float vhi = __shfl(v, 2 * t + 1, 64);
        if (lane < 16) hw2p[(size_t)n * 16 + lane] = pack_bf16(vlo, vhi);
    }
}

// ---------- layer 2 aggregation + bias + relu -> out --------------------------
__global__ __launch_bounds__(256) void k_agg2(
        const int* __restrict__ rowptr, const uint2* __restrict__ csr,
        const uint4* __restrict__ hw2p4, const float* __restrict__ dinv,
        const float* __restrict__ b2, float* __restrict__ out) {
    int n = (blockIdx.x * blockDim.x + threadIdx.x) >> 6;
    if (n >= NN) return;
    int lane = threadIdx.x & 63;
    int s = lane >> 2;
    int u = lane & 3;
    int beg = rowptr[n], end = rowptr[n + 1];
    float dn = dinv[n];
    uint4 gs = hw2p4[(size_t)n * 4 + u];
    float c0 = 0.f, c1 = 0.f, c2 = 0.f, c3 = 0.f;
    float c4 = 0.f, c5 = 0.f, c6 = 0.f, c7 = 0.f;
    float d0 = 0.f, d1 = 0.f, d2 = 0.f, d3 = 0.f;
    float d4 = 0.f, d5 = 0.f, d6 = 0.f, d7 = 0.f;
    int j = beg + s;
    for (; j + 16 < end; j += 32) {
        uint2 e0 = csr[j];
        uint2 e1 = csr[j + 16];
        uint4 g0 = hw2p4[(size_t)e0.x * 4 + u];
        uint4 g1 = hw2p4[(size_t)e1.x * 4 + u];
        float w0 = __uint_as_float(e0.y);
        float w1 = __uint_as_float(e1.y);
        c0 = fmaf(w0, lo16(g0.x), c0);
        c1 = fmaf(w0, hi16(g0.x), c1);
        c2 = fmaf(w0, lo16(g0.y), c2);
        c3 = fmaf(w0, hi16(g0.y), c3);
        c4 = fmaf(w0, lo16(g0.z), c4);
        c5 = fmaf(w0, hi16(g0.z), c5);
        c6 = fmaf(w0, lo16(g0.w), c6);
        c7 = fmaf(w0, hi16(g0.w), c7);
        d0 = fmaf(w1, lo16(g1.x), d0);
        d1 = fmaf(w1, hi16(g1.x), d1);
        d2 = fmaf(w1, lo16(g1.y), d2);
        d3 = fmaf(w1, hi16(g1.y), d3);
        d4 = fmaf(w1, lo16(g1.z), d4);
        d5 = fmaf(w1, hi16(g1.z), d5);
        d6 = fmaf(w1, lo16(g1.w), d6);
        d7 = fmaf(w1, hi16(g1.w), d7);
    }
    for (; j < end; j += 16) {
        uint2 e = csr[j];
        uint4 g = hw2p4[(size_t)e.x * 4 + u];
        float w = __uint_as_float(e.y);
        c0 = fmaf(w, lo16(g.x), c0);
        c1 = fmaf(w, hi16(g.x), c1);
        c2 = fmaf(w, lo16(g.y), c2);
        c3 = fmaf(w, hi16(g.y), c3);
        c4 = fmaf(w, lo16(g.z), c4);
        c5 = fmaf(w, hi16(g.z), c5);
        c6 = fmaf(w, lo16(g.w), c6);
        c7 = fmaf(w, hi16(g.w), c7);
    }
    c0 += d0; c1 += d1; c2 += d2; c3 += d3;
    c4 += d4; c5 += d5; c6 += d6; c7 += d7;
#pragma unroll
    for (int m = 4; m <= 32; m <<= 1) {
        c0 += __shfl_xor(c0, m, 64);
        c1 += __shfl_xor(c1, m, 64);
        c2 += __shfl_xor(c2, m, 64);
        c3 += __shfl_xor(c3, m, 64);
        c4 += __shfl_xor(c4, m, 64);
        c5 += __shfl_xor(c5, m, 64);
        c6 += __shfl_xor(c6, m, 64);
        c7 += __shfl_xor(c7, m, 64);
    }
    if (s == 0) {                                   // lanes 0..3: 8 outputs each
        float4 bq0 = ((const float4*)b2)[2 * u];
        float4 bq1 = ((const float4*)b2)[2 * u + 1];
        float4 v0, v1;
        v0.x = dn * (c0 + lo16(gs.x)) + bq0.x;
        v0.y = dn * (c1 + hi16(gs.x)) + bq0.y;
        v0.z = dn * (c2 + lo16(gs.y)) + bq0.z;
        v0.w = dn * (c3 + hi16(gs.y)) + bq0.w;
        v1.x = dn * (c4 + lo16(gs.z)) + bq1.x;
        v1.y = dn * (c5 + hi16(gs.z)) + bq1.y;
        v1.z = dn * (c6 + lo16(gs.w)) + bq1.z;
        v1.w = dn * (c7 + hi16(gs.w)) + bq1.w;
        v0.x = v0.x > 0.f ? v0.x : 0.f;
        v0.y = v0.y > 0.f ? v0.y : 0.f;
        v0.z = v0.z > 0.f ? v0.z : 0.f;
        v0.w = v0.w > 0.f ? v0.w : 0.f;
        v1.x = v1.x > 0.f ? v1.x : 0.f;
        v1.y = v1.y > 0.f ? v1.y : 0.f;
        v1.z = v1.z > 0.f ? v1.z : 0.f;
        v1.w = v1.w > 0.f ? v1.w : 0.f;
        ((float4*)out)[(size_t)n * 8 + 2 * u] = v0;
        ((float4*)out)[(size_t)n * 8 + 2 * u + 1] = v1;
    }
}

extern "C" void kernel_launch(void* const* d_in, const int* in_sizes, int n_in,
                              void* d_out, int out_size, void* d_ws, size_t ws_size,
                              hipStream_t stream) {
    const float* x  = (const float*)d_in[0];
    const int*   ei = (const int*)d_in[1];
    const float* ea = (const float*)d_in[2];
    const float* W1 = (const float*)d_in[3];
    const float* b1 = (const float*)d_in[4];
    const float* W2 = (const float*)d_in[5];
    const float* b2 = (const float*)d_in[6];
    float* out = (float*)d_out;

    const int* row = ei;        // edge_index[0]
    const int* col = ei + NE;   // edge_index[1]

    // workspace layout (~41 MB)
    char* w = (char*)d_ws;
    uint2* rec0     = (uint2*)w;                         // NE*8
    uint2* csr      = rec0 + NE;                         // NE*8
    unsigned* xp    = (unsigned*)(csr + NE);             // NN*16 (bf16x2)
    unsigned* hw2p  = xp + (size_t)NN * 16;              // NN*16 (bf16x2)
    float* dinv     = (float*)(hw2p + (size_t)NN * 16);  // NN
    int*   rowptr   = (int*)(dinv + NN);                 // NN+1
    int*   hist_g   = rowptr + NN + 1;                   // NSC
    int*   scng     = hist_g + NSC;                      // NSC
    int*   bsum     = scng + NSC;                        // 256

    auto cdiv = [](long long a, int b) { return (int)((a + b - 1) / b); };

    // independent: edge_attr passthrough
    hipMemcpyAsync(out + (size_t)NN * FIN, ea, sizeof(float) * (size_t)NE,
                   hipMemcpyDeviceToDevice, stream);

    // deterministic counting-sort build (no global atomics)
    k_dcount<<<NDB, 256, 0, stream>>>(col, hist_g);
    k_scan1<<<SCAN_NB, SCAN_B, 0, stream>>>(hist_g, scng, bsum);
    k_scan2<<<1, 256, 0, stream>>>(bsum);
    k_scan3<<<cdiv(NSC, 256), 256, 0, stream>>>(scng, bsum);
    k_dwrite<<<NDB, 256, 0, stream>>>(row, col, ea, scng, rec0);
    k_bsort<<<NB, 256, 0, stream>>>(scng, rec0, csr, rowptr, dinv);

    // fold src-side norm into x, pack bf16x2
    k_scalex<<<cdiv((long long)NN * (FIN / 2), 256), 256, 0, stream>>>(x, dinv, xp);

    // layer 1 fused (agg + GEMM1 + GEMM2 + dst scale) -> hw2p (bf16x2)
    const int A1_BLOCKS = 2048;
    k_agg1f<<<A1_BLOCKS, 256, 0, stream>>>(rowptr, csr, (const uint4*)xp, dinv,
                                           W1, b1, W2, hw2p, A1_BLOCKS * 4);

    // layer 2 aggregation -> out
    k_agg2<<<cdiv((long long)NN * 64, 256), 256, 0, stream>>>(
        rowptr, csr, (const uint4*)hw2p, dinv, b2, out);
}